// Round 6
// baseline (3370.137 us; speedup 1.0000x reference)
//
#include <hip/hip_runtime.h>
#include <cstdint>
#include <cstddef>

#define B_ 64
#define T_ 2048
#define I_ 256
#define H_ 256
#define G_ 768   // 3*H

typedef _Float16 h2v __attribute__((ext_vector_type(2)));
typedef _Float16 v8h __attribute__((ext_vector_type(8)));
typedef float    v4f __attribute__((ext_vector_type(4)));
typedef uint32_t u32x4 __attribute__((ext_vector_type(4)));

union U32h { uint32_t u; h2v h; };

// ---------------------------------------------------------------------------
// prep: Whh fp32 [768][256] -> MFMA A-fragment layout (16x16x32 f16).
// Fragment (rt, kb), rt in [0,48), kb in [0,8):
//   lane l element e holds A[row][k] with row = rt*16 + (l&15),
//   k = kb*32 + (l>>4)*8 + e. Byte addr: Wp + ((rt*8+kb)*64 + l)*16.
// Verified numerically in round 3 (kernel passed with this layout).
// ---------------------------------------------------------------------------
__global__ void prep_whh_frag(const float* __restrict__ Whh, uint32_t* __restrict__ Wp) {
    int rt = blockIdx.x;           // 0..47
    int kb = blockIdx.y;           // 0..7
    int lane = threadIdx.x;        // 0..63
    int r16 = lane & 15, hi2 = lane >> 4;
    const float* src = Whh + (size_t)(rt * 16 + r16) * 256 + kb * 32 + hi2 * 8;
    uint32_t d[4];
    for (int p = 0; p < 4; ++p) {
        U32h u; u.h = h2v{(_Float16)src[2 * p], (_Float16)src[2 * p + 1]};
        d[p] = u.u;
    }
    *(u32x4*)(Wp + (((size_t)rt * 8 + kb) * 64 + lane) * 4) = u32x4{d[0], d[1], d[2], d[3]};
}

// ---------------------------------------------------------------------------
// gi GEMM: gi[t_local*64 + b][n].  b_hh folded into the bias for gates r
// (n<256) and u (n>=512) — exact (they only appear as g + dot + bh). Gate
// c's b_hh[256:512] stays separate (it is inside r*(dot+bh1)).
// ---------------------------------------------------------------------------
#define LDA 56
#define LDB 56

__launch_bounds__(256, 2)
__global__ void gemm_gi(const float* __restrict__ x, const float* __restrict__ Wih,
                        const float* __restrict__ bih, const float* __restrict__ bhh,
                        _Float16* __restrict__ gi, int t0) {
    __shared__ __align__(16) _Float16 As[64 * LDA];
    __shared__ __align__(16) _Float16 Bs[384 * LDB];
    int tid  = threadIdx.x;
    int t    = t0 + blockIdx.x;
    int n0   = blockIdx.y * 384;
    int lane = tid & 63, wave = tid >> 6;
    int quad = lane >> 4, r16 = lane & 15;

    v4f acc[24];
#pragma unroll
    for (int i = 0; i < 24; ++i) acc[i] = v4f{0.f, 0.f, 0.f, 0.f};

    for (int ki = 0; ki < 8; ++ki) {
        int k0 = ki * 32;
        __syncthreads();
#pragma unroll
        for (int s = 0; s < 2; ++s) {
            int slot = tid + s * 256;
            int row = slot >> 3;
            int part = slot & 7;
            const float* xp = x + ((size_t)row * T_ + t) * I_ + k0 + part * 4;
            float4 v = *(const float4*)xp;
            U32h u0, u1;
            u0.h = h2v{(_Float16)v.x, (_Float16)v.y};
            u1.h = h2v{(_Float16)v.z, (_Float16)v.w};
            uint32_t* dst = (uint32_t*)&As[row * LDA + part * 4];
            dst[0] = u0.u; dst[1] = u1.u;
        }
#pragma unroll
        for (int s = 0; s < 12; ++s) {
            int slot = tid + s * 256;
            int row = slot >> 3;
            int part = slot & 7;
            const float* wp = Wih + (size_t)(n0 + row) * I_ + k0 + part * 4;
            float4 v = *(const float4*)wp;
            U32h u0, u1;
            u0.h = h2v{(_Float16)v.x, (_Float16)v.y};
            u1.h = h2v{(_Float16)v.z, (_Float16)v.w};
            uint32_t* dst = (uint32_t*)&Bs[row * LDB + part * 4];
            dst[0] = u0.u; dst[1] = u1.u;
        }
        __syncthreads();
        v8h af = *(const v8h*)&As[(wave * 16 + r16) * LDA + quad * 8];
#pragma unroll
        for (int nt = 0; nt < 24; ++nt) {
            v8h bf = *(const v8h*)&Bs[(nt * 16 + r16) * LDB + quad * 8];
            acc[nt] = __builtin_amdgcn_mfma_f32_16x16x32_f16(af, bf, acc[nt], 0, 0, 0);
        }
    }
#pragma unroll
    for (int nt = 0; nt < 24; ++nt) {
        int n = n0 + nt * 16 + r16;
        float bias = bih[n] + ((n < 256 || n >= 512) ? bhh[n] : 0.0f);
#pragma unroll
        for (int reg = 0; reg < 4; ++reg) {
            int m = wave * 16 + quad * 4 + reg;
            size_t off = ((size_t)blockIdx.x * 64 + m) * G_ + n;
            gi[off] = (_Float16)(acc[nt][reg] + bias);
        }
    }
}

// ---------------------------------------------------------------------------
// Recurrent kernel v8 = v7 + two correctness fixes (v7 produced NaN):
//  FIX 1: hb must be 1024-ALIGNED — the double-buffer toggle is
//         v_xor_b32 addr,0x200, which maps buf0<->buf1 only when bit 9 of
//         the base is 0. With only align(16), LDS lowering could place hb
//         at a bit-9-set offset -> XOR jumped outside hb into garbage LDS
//         -> f16 NaN patterns -> MFMA propagated NaN (the observed fail).
//  FIX 2: WAR hazard — pass-0's ds_write_b128 of v[52:63] was followed
//         immediately by re-zeroing v[52:63] for pass 1; DS writes consume
//         their data VGPRs asynchronously (released per lgkmcnt), so the
//         zeros could corrupt ypart. Added s_waitcnt lgkmcnt(0) between.
// Everything else unchanged from v7 (see its header comment for the
// allocator-war rationale and the wave/row-tile geometry).
// ---------------------------------------------------------------------------
__global__ void __launch_bounds__(512)
rec_step(const uint32_t* __restrict__ Wfrag, const float* __restrict__ bhh,
         const _Float16* __restrict__ gi, const float* __restrict__ h_init,
         float* __restrict__ out, float* __restrict__ hN,
         float* __restrict__ h_carry, int t0, int len) {
    __shared__ __align__(1024) _Float16 hb[2][256];  // 1024 B, MUST be 1024-aligned (XOR 0x200 toggle)
    __shared__ __align__(16) float ypart[G_];        // 3072 B
    __shared__ __align__(16) float dump[2176];       // 8704 B scatter sink

    int b = blockIdx.x;
    int tid = threadIdx.x;
    int lane = tid & 63, wave = tid >> 6;
    int r16 = lane & 15, hi2 = lane >> 4;
    int j = tid & 255;

    uint32_t ldsHb = (uint32_t)(uintptr_t)&hb[0][0];
    uint32_t ldsYp = (uint32_t)(uintptr_t)&ypart[0];
    uint32_t ldsDp = (uint32_t)(uintptr_t)&dump[0];

    uint32_t hrd = ldsHb + hi2 * 16;                       // bf read base (cur=0)
    uint32_t hwr = ldsHb + 512 + j * 2;                    // h write (cur^1=1)
    uint32_t ypw = (r16 == 0) ? (ldsYp + wave * 384 + hi2 * 16)
                              : (ldsDp + (wave * 64 + lane) * 16);
    uint32_t ypr = ldsYp + j * 4;

    uint64_t wad = (uint64_t)(uintptr_t)Wfrag + ((uint64_t)wave * 48 * 64 + lane) * 16;
    uint64_t oad = (uint64_t)(uintptr_t)out + (((uint64_t)b * T_ + t0) * H_ + j) * 4;
    uint64_t gad = (uint64_t)(uintptr_t)gi + ((uint64_t)b * G_ + j) * 2;

    float hp  = h_init[b * 256 + j];
    float bh1 = bhh[256 + j];
    if (tid < 256) hb[0][j] = (_Float16)hp;
    __syncthreads();

    float hout;
    asm volatile(
        // ---- register setup ----
        "v_lshlrev_b64 v[40:41], 0, %[oad]\n\t"
        "v_lshlrev_b64 v[42:43], 0, %[gad]\n\t"
        "v_lshlrev_b64 v[28:29], 0, %[wad]\n\t"
        "v_mov_b32 v36, %[hrd]\n\t"
        "v_mov_b32 v37, %[ypw]\n\t"
        "v_mov_b32 v38, %[ypr]\n\t"
        "v_mov_b32 v39, %[hwr]\n\t"
        "v_mov_b32 v51, %[bh1]\n\t"
        "v_mov_b32 v47, %[hp]\n\t"
        "s_mov_b32 s80, %[len]\n\t"
        // ---- load 48 A-fragments: v[64:255], 12 groups of 4 x dwordx4 ----
        "global_load_dwordx4 v[64:67], v[28:29], off\n\t"
        "global_load_dwordx4 v[68:71], v[28:29], off offset:1024\n\t"
        "global_load_dwordx4 v[72:75], v[28:29], off offset:2048\n\t"
        "global_load_dwordx4 v[76:79], v[28:29], off offset:3072\n\t"
        "v_add_co_u32 v28, vcc, 0x1000, v28\n\t"
        "v_addc_co_u32 v29, vcc, 0, v29, vcc\n\t"
        "global_load_dwordx4 v[80:83], v[28:29], off\n\t"
        "global_load_dwordx4 v[84:87], v[28:29], off offset:1024\n\t"
        "global_load_dwordx4 v[88:91], v[28:29], off offset:2048\n\t"
        "global_load_dwordx4 v[92:95], v[28:29], off offset:3072\n\t"
        "v_add_co_u32 v28, vcc, 0x1000, v28\n\t"
        "v_addc_co_u32 v29, vcc, 0, v29, vcc\n\t"
        "global_load_dwordx4 v[96:99], v[28:29], off\n\t"
        "global_load_dwordx4 v[100:103], v[28:29], off offset:1024\n\t"
        "global_load_dwordx4 v[104:107], v[28:29], off offset:2048\n\t"
        "global_load_dwordx4 v[108:111], v[28:29], off offset:3072\n\t"
        "v_add_co_u32 v28, vcc, 0x1000, v28\n\t"
        "v_addc_co_u32 v29, vcc, 0, v29, vcc\n\t"
        "global_load_dwordx4 v[112:115], v[28:29], off\n\t"
        "global_load_dwordx4 v[116:119], v[28:29], off offset:1024\n\t"
        "global_load_dwordx4 v[120:123], v[28:29], off offset:2048\n\t"
        "global_load_dwordx4 v[124:127], v[28:29], off offset:3072\n\t"
        "v_add_co_u32 v28, vcc, 0x1000, v28\n\t"
        "v_addc_co_u32 v29, vcc, 0, v29, vcc\n\t"
        "global_load_dwordx4 v[128:131], v[28:29], off\n\t"
        "global_load_dwordx4 v[132:135], v[28:29], off offset:1024\n\t"
        "global_load_dwordx4 v[136:139], v[28:29], off offset:2048\n\t"
        "global_load_dwordx4 v[140:143], v[28:29], off offset:3072\n\t"
        "v_add_co_u32 v28, vcc, 0x1000, v28\n\t"
        "v_addc_co_u32 v29, vcc, 0, v29, vcc\n\t"
        "global_load_dwordx4 v[144:147], v[28:29], off\n\t"
        "global_load_dwordx4 v[148:151], v[28:29], off offset:1024\n\t"
        "global_load_dwordx4 v[152:155], v[28:29], off offset:2048\n\t"
        "global_load_dwordx4 v[156:159], v[28:29], off offset:3072\n\t"
        "v_add_co_u32 v28, vcc, 0x1000, v28\n\t"
        "v_addc_co_u32 v29, vcc, 0, v29, vcc\n\t"
        "global_load_dwordx4 v[160:163], v[28:29], off\n\t"
        "global_load_dwordx4 v[164:167], v[28:29], off offset:1024\n\t"
        "global_load_dwordx4 v[168:171], v[28:29], off offset:2048\n\t"
        "global_load_dwordx4 v[172:175], v[28:29], off offset:3072\n\t"
        "v_add_co_u32 v28, vcc, 0x1000, v28\n\t"
        "v_addc_co_u32 v29, vcc, 0, v29, vcc\n\t"
        "global_load_dwordx4 v[176:179], v[28:29], off\n\t"
        "global_load_dwordx4 v[180:183], v[28:29], off offset:1024\n\t"
        "global_load_dwordx4 v[184:187], v[28:29], off offset:2048\n\t"
        "global_load_dwordx4 v[188:191], v[28:29], off offset:3072\n\t"
        "v_add_co_u32 v28, vcc, 0x1000, v28\n\t"
        "v_addc_co_u32 v29, vcc, 0, v29, vcc\n\t"
        "global_load_dwordx4 v[192:195], v[28:29], off\n\t"
        "global_load_dwordx4 v[196:199], v[28:29], off offset:1024\n\t"
        "global_load_dwordx4 v[200:203], v[28:29], off offset:2048\n\t"
        "global_load_dwordx4 v[204:207], v[28:29], off offset:3072\n\t"
        "v_add_co_u32 v28, vcc, 0x1000, v28\n\t"
        "v_addc_co_u32 v29, vcc, 0, v29, vcc\n\t"
        "global_load_dwordx4 v[208:211], v[28:29], off\n\t"
        "global_load_dwordx4 v[212:215], v[28:29], off offset:1024\n\t"
        "global_load_dwordx4 v[216:219], v[28:29], off offset:2048\n\t"
        "global_load_dwordx4 v[220:223], v[28:29], off offset:3072\n\t"
        "v_add_co_u32 v28, vcc, 0x1000, v28\n\t"
        "v_addc_co_u32 v29, vcc, 0, v29, vcc\n\t"
        "global_load_dwordx4 v[224:227], v[28:29], off\n\t"
        "global_load_dwordx4 v[228:231], v[28:29], off offset:1024\n\t"
        "global_load_dwordx4 v[232:235], v[28:29], off offset:2048\n\t"
        "global_load_dwordx4 v[236:239], v[28:29], off offset:3072\n\t"
        "v_add_co_u32 v28, vcc, 0x1000, v28\n\t"
        "v_addc_co_u32 v29, vcc, 0, v29, vcc\n\t"
        "global_load_dwordx4 v[240:243], v[28:29], off\n\t"
        "global_load_dwordx4 v[244:247], v[28:29], off offset:1024\n\t"
        "global_load_dwordx4 v[248:251], v[28:29], off offset:2048\n\t"
        "global_load_dwordx4 v[252:255], v[28:29], off offset:3072\n\t"
        // ---- g(0) ----
        "global_load_ushort v48, v[42:43], off\n\t"
        "global_load_ushort v49, v[42:43], off offset:512\n\t"
        "global_load_ushort v50, v[42:43], off offset:1024\n\t"
        "v_add_co_u32 v42, vcc, 0x18000, v42\n\t"
        "v_addc_co_u32 v43, vcc, 0, v43, vcc\n\t"
        "s_waitcnt vmcnt(0)\n\t"
        "v_cvt_f32_f16 v44, v48\n\t"
        "v_cvt_f32_f16 v45, v49\n\t"
        "v_cvt_f32_f16 v46, v50\n\t"
        "s_nop 3\n\t"
        // ==================== t-loop ====================
        "9:\n\t"
        // prefetch g(t+1)
        "global_load_ushort v48, v[42:43], off\n\t"
        "global_load_ushort v49, v[42:43], off offset:512\n\t"
        "global_load_ushort v50, v[42:43], off offset:1024\n\t"
        // ---- pass 0: row-tiles 0..2 ----
        "v_mov_b32 v52, 0\n\t" "v_mov_b32 v53, 0\n\t" "v_mov_b32 v54, 0\n\t" "v_mov_b32 v55, 0\n\t"
        "v_mov_b32 v56, 0\n\t" "v_mov_b32 v57, 0\n\t" "v_mov_b32 v58, 0\n\t" "v_mov_b32 v59, 0\n\t"
        "v_mov_b32 v60, 0\n\t" "v_mov_b32 v61, 0\n\t" "v_mov_b32 v62, 0\n\t" "v_mov_b32 v63, 0\n\t"
        "ds_read_b128 v[28:31], v36\n\t"
        "ds_read_b128 v[32:35], v36 offset:64\n\t"
        "s_waitcnt lgkmcnt(1)\n\t"
        "v_mfma_f32_16x16x32_f16 v[52:55], v[64:67], v[28:31], v[52:55]\n\t"
        "v_mfma_f32_16x16x32_f16 v[56:59], v[96:99], v[28:31], v[56:59]\n\t"
        "v_mfma_f32_16x16x32_f16 v[60:63], v[128:131], v[28:31], v[60:63]\n\t"
        "ds_read_b128 v[28:31], v36 offset:128\n\t"
        "s_waitcnt lgkmcnt(1)\n\t"
        "v_mfma_f32_16x16x32_f16 v[52:55], v[68:71], v[32:35], v[52:55]\n\t"
        "v_mfma_f32_16x16x32_f16 v[56:59], v[100:103], v[32:35], v[56:59]\n\t"
        "v_mfma_f32_16x16x32_f16 v[60:63], v[132:135], v[32:35], v[60:63]\n\t"
        "ds_read_b128 v[32:35], v36 offset:192\n\t"
        "s_waitcnt lgkmcnt(1)\n\t"
        "v_mfma_f32_16x16x32_f16 v[52:55], v[72:75], v[28:31], v[52:55]\n\t"
        "v_mfma_f32_16x16x32_f16 v[56:59], v[104:107], v[28:31], v[56:59]\n\t"
        "v_mfma_f32_16x16x32_f16 v[60:63], v[136:139], v[28:31], v[60:63]\n\t"
        "ds_read_b128 v[28:31], v36 offset:256\n\t"
        "s_waitcnt lgkmcnt(1)\n\t"
        "v_mfma_f32_16x16x32_f16 v[52:55], v[76:79], v[32:35], v[52:55]\n\t"
        "v_mfma_f32_16x16x32_f16 v[56:59], v[108:111], v[32:35], v[56:59]\n\t"
        "v_mfma_f32_16x16x32_f16 v[60:63], v[140:143], v[32:35], v[60:63]\n\t"
        "ds_read_b128 v[32:35], v36 offset:320\n\t"
        "s_waitcnt lgkmcnt(1)\n\t"
        "v_mfma_f32_16x16x32_f16 v[52:55], v[80:83], v[28:31], v[52:55]\n\t"
        "v_mfma_f32_16x16x32_f16 v[56:59], v[112:115], v[28:31], v[56:59]\n\t"
        "v_mfma_f32_16x16x32_f16 v[60:63], v[144:147], v[28:31], v[60:63]\n\t"
        "ds_read_b128 v[28:31], v36 offset:384\n\t"
        "s_waitcnt lgkmcnt(1)\n\t"
        "v_mfma_f32_16x16x32_f16 v[52:55], v[84:87], v[32:35], v[52:55]\n\t"
        "v_mfma_f32_16x16x32_f16 v[56:59], v[116:119], v[32:35], v[56:59]\n\t"
        "v_mfma_f32_16x16x32_f16 v[60:63], v[148:151], v[32:35], v[60:63]\n\t"
        "ds_read_b128 v[32:35], v36 offset:448\n\t"
        "s_waitcnt lgkmcnt(1)\n\t"
        "v_mfma_f32_16x16x32_f16 v[52:55], v[88:91], v[28:31], v[52:55]\n\t"
        "v_mfma_f32_16x16x32_f16 v[56:59], v[120:123], v[28:31], v[56:59]\n\t"
        "v_mfma_f32_16x16x32_f16 v[60:63], v[152:155], v[28:31], v[60:63]\n\t"
        "s_waitcnt lgkmcnt(0)\n\t"
        "v_mfma_f32_16x16x32_f16 v[52:55], v[92:95], v[32:35], v[52:55]\n\t"
        "v_mfma_f32_16x16x32_f16 v[56:59], v[124:127], v[32:35], v[56:59]\n\t"
        "v_mfma_f32_16x16x32_f16 v[60:63], v[156:159], v[32:35], v[60:63]\n\t"
        "s_nop 7\n\t"
        "s_nop 7\n\t"
        "ds_write_b128 v37, v[52:55]\n\t"
        "ds_write_b128 v37, v[56:59] offset:64\n\t"
        "ds_write_b128 v37, v[60:63] offset:128\n\t"
        "s_waitcnt lgkmcnt(0)\n\t"      // FIX 2: release v52-63 before re-zeroing (WAR)
        // ---- pass 1: row-tiles 3..5 ----
        "v_mov_b32 v52, 0\n\t" "v_mov_b32 v53, 0\n\t" "v_mov_b32 v54, 0\n\t" "v_mov_b32 v55, 0\n\t"
        "v_mov_b32 v56, 0\n\t" "v_mov_b32 v57, 0\n\t" "v_mov_b32 v58, 0\n\t" "v_mov_b32 v59, 0\n\t"
        "v_mov_b32 v60, 0\n\t" "v_mov_b32 v61, 0\n\t" "v_mov_b32 v62, 0\n\t" "v_mov_b32 v63, 0\n\t"
        "ds_read_b128 v[28:31], v36\n\t"
        "ds_read_b128 v[32:35], v36 offset:64\n\t"
        "s_waitcnt lgkmcnt(1)\n\t"
        "v_mfma_f32_16x16x32_f16 v[52:55], v[160:163], v[28:31], v[52:55]\n\t"
        "v_mfma_f32_16x16x32_f16 v[56:59], v[192:195], v[28:31], v[56:59]\n\t"
        "v_mfma_f32_16x16x32_f16 v[60:63], v[224:227], v[28:31], v[60:63]\n\t"
        "ds_read_b128 v[28:31], v36 offset:128\n\t"
        "s_waitcnt lgkmcnt(1)\n\t"
        "v_mfma_f32_16x16x32_f16 v[52:55], v[164:167], v[32:35], v[52:55]\n\t"
        "v_mfma_f32_16x16x32_f16 v[56:59], v[196:199], v[32:35], v[56:59]\n\t"
        "v_mfma_f32_16x16x32_f16 v[60:63], v[228:231], v[32:35], v[60:63]\n\t"
        "ds_read_b128 v[32:35], v36 offset:192\n\t"
        "s_waitcnt lgkmcnt(1)\n\t"
        "v_mfma_f32_16x16x32_f16 v[52:55], v[168:171], v[28:31], v[52:55]\n\t"
        "v_mfma_f32_16x16x32_f16 v[56:59], v[200:203], v[28:31], v[56:59]\n\t"
        "v_mfma_f32_16x16x32_f16 v[60:63], v[232:235], v[28:31], v[60:63]\n\t"
        "ds_read_b128 v[28:31], v36 offset:256\n\t"
        "s_waitcnt lgkmcnt(1)\n\t"
        "v_mfma_f32_16x16x32_f16 v[52:55], v[172:175], v[32:35], v[52:55]\n\t"
        "v_mfma_f32_16x16x32_f16 v[56:59], v[204:207], v[32:35], v[56:59]\n\t"
        "v_mfma_f32_16x16x32_f16 v[60:63], v[236:239], v[32:35], v[60:63]\n\t"
        "ds_read_b128 v[32:35], v36 offset:320\n\t"
        "s_waitcnt lgkmcnt(1)\n\t"
        "v_mfma_f32_16x16x32_f16 v[52:55], v[176:179], v[28:31], v[52:55]\n\t"
        "v_mfma_f32_16x16x32_f16 v[56:59], v[208:211], v[28:31], v[56:59]\n\t"
        "v_mfma_f32_16x16x32_f16 v[60:63], v[240:243], v[28:31], v[60:63]\n\t"
        "ds_read_b128 v[28:31], v36 offset:384\n\t"
        "s_waitcnt lgkmcnt(1)\n\t"
        "v_mfma_f32_16x16x32_f16 v[52:55], v[180:183], v[32:35], v[52:55]\n\t"
        "v_mfma_f32_16x16x32_f16 v[56:59], v[212:215], v[32:35], v[56:59]\n\t"
        "v_mfma_f32_16x16x32_f16 v[60:63], v[244:247], v[32:35], v[60:63]\n\t"
        "ds_read_b128 v[32:35], v36 offset:448\n\t"
        "s_waitcnt lgkmcnt(1)\n\t"
        "v_mfma_f32_16x16x32_f16 v[52:55], v[184:187], v[28:31], v[52:55]\n\t"
        "v_mfma_f32_16x16x32_f16 v[56:59], v[216:219], v[28:31], v[56:59]\n\t"
        "v_mfma_f32_16x16x32_f16 v[60:63], v[248:251], v[28:31], v[60:63]\n\t"
        "s_waitcnt lgkmcnt(0)\n\t"
        "v_mfma_f32_16x16x32_f16 v[52:55], v[188:191], v[32:35], v[52:55]\n\t"
        "v_mfma_f32_16x16x32_f16 v[56:59], v[220:223], v[32:35], v[56:59]\n\t"
        "v_mfma_f32_16x16x32_f16 v[60:63], v[252:255], v[32:35], v[60:63]\n\t"
        "s_nop 7\n\t"
        "s_nop 7\n\t"
        "ds_write_b128 v37, v[52:55] offset:192\n\t"
        "ds_write_b128 v37, v[56:59] offset:256\n\t"
        "ds_write_b128 v37, v[60:63] offset:320\n\t"
        "s_waitcnt lgkmcnt(0)\n\t"
        "s_barrier\n\t"
        // ---- pointwise (all 512 threads, duplicates benign) ----
        "ds_read_b32 v28, v38\n\t"
        "ds_read_b32 v29, v38 offset:1024\n\t"
        "ds_read_b32 v30, v38 offset:2048\n\t"
        "s_waitcnt lgkmcnt(0)\n\t"
        "v_add_f32 v31, v44, v28\n\t"               // g0 + s0
        "v_mul_f32 v31, 0xbfb8aa3b, v31\n\t"        // * -log2(e)
        "v_exp_f32 v31, v31\n\t"
        "s_nop 1\n\t"
        "v_add_f32 v31, 1.0, v31\n\t"
        "v_rcp_f32 v31, v31\n\t"                    // r
        "s_nop 1\n\t"
        "v_add_f32 v32, v46, v30\n\t"               // g2 + s2
        "v_mul_f32 v32, 0xbfb8aa3b, v32\n\t"
        "v_exp_f32 v32, v32\n\t"
        "s_nop 1\n\t"
        "v_add_f32 v32, 1.0, v32\n\t"
        "v_rcp_f32 v32, v32\n\t"                    // u
        "s_nop 1\n\t"
        "v_add_f32 v33, v29, v51\n\t"               // s1 + bh1
        "v_mov_b32 v34, v45\n\t"
        "v_fmac_f32 v34, v31, v33\n\t"              // carg = g1 + r*(s1+bh1)
        "v_mul_f32 v34, 0x4038aa3b, v34\n\t"        // * 2*log2(e)
        "v_exp_f32 v34, v34\n\t"                    // e2 (inf-safe)
        "s_nop 1\n\t"
        "v_add_f32 v34, 1.0, v34\n\t"
        "v_rcp_f32 v34, v34\n\t"
        "s_nop 1\n\t"
        "v_mov_b32 v35, 1.0\n\t"
        "v_fmac_f32 v35, -2.0, v34\n\t"             // n = 1 - 2/(e2+1)
        "v_sub_f32 v28, v35, v47\n\t"               // n - hprev
        "v_mov_b32 v29, v47\n\t"
        "v_fmac_f32 v29, v32, v28\n\t"              // hnew
        "s_waitcnt vmcnt(0)\n\t"
        "v_cvt_f32_f16 v44, v48\n\t"                // g <- prefetched
        "v_cvt_f32_f16 v45, v49\n\t"
        "v_cvt_f32_f16 v46, v50\n\t"
        "global_store_dword v[40:41], v29, off\n\t"
        "v_add_co_u32 v40, vcc, 0x400, v40\n\t"
        "v_addc_co_u32 v41, vcc, 0, v41, vcc\n\t"
        "v_cvt_f16_f32 v30, v29\n\t"
        "ds_write_b16 v39, v30\n\t"
        "v_mov_b32 v47, v29\n\t"
        "v_add_co_u32 v42, vcc, 0x18000, v42\n\t"
        "v_addc_co_u32 v43, vcc, 0, v43, vcc\n\t"
        "v_xor_b32 v36, 0x200, v36\n\t"
        "v_xor_b32 v39, 0x200, v39\n\t"
        "s_waitcnt lgkmcnt(0)\n\t"
        "s_barrier\n\t"
        "s_sub_u32 s80, s80, 1\n\t"
        "s_cmp_lg_u32 s80, 0\n\t"
        "s_cbranch_scc1 9b\n\t"
        "s_waitcnt vmcnt(0) lgkmcnt(0)\n\t"
        "v_mov_b32 %[hout], v47\n\t"
        : [hout] "=v"(hout)
        : [wad] "v"(wad), [oad] "v"(oad), [gad] "v"(gad),
          [hrd] "v"(hrd), [ypw] "v"(ypw), [ypr] "v"(ypr), [hwr] "v"(hwr),
          [bh1] "v"(bh1), [hp] "v"(hp), [len] "s"(len)
        : "memory", "vcc", "scc", "s80",
          "v28","v29","v30","v31","v32","v33","v34","v35",
          "v36","v37","v38","v39","v40","v41","v42","v43",
          "v44","v45","v46","v47","v48","v49","v50","v51",
          "v52","v53","v54","v55","v56","v57","v58","v59",
          "v60","v61","v62","v63","v64","v65","v66","v67",
          "v68","v69","v70","v71","v72","v73","v74","v75",
          "v76","v77","v78","v79","v80","v81","v82","v83",
          "v84","v85","v86","v87","v88","v89","v90","v91",
          "v92","v93","v94","v95","v96","v97","v98","v99",
          "v100","v101","v102","v103","v104","v105","v106","v107",
          "v108","v109","v110","v111","v112","v113","v114","v115",
          "v116","v117","v118","v119","v120","v121","v122","v123",
          "v124","v125","v126","v127","v128","v129","v130","v131",
          "v132","v133","v134","v135","v136","v137","v138","v139",
          "v140","v141","v142","v143","v144","v145","v146","v147",
          "v148","v149","v150","v151","v152","v153","v154","v155",
          "v156","v157","v158","v159","v160","v161","v162","v163",
          "v164","v165","v166","v167","v168","v169","v170","v171",
          "v172","v173","v174","v175","v176","v177","v178","v179",
          "v180","v181","v182","v183","v184","v185","v186","v187",
          "v188","v189","v190","v191","v192","v193","v194","v195",
          "v196","v197","v198","v199","v200","v201","v202","v203",
          "v204","v205","v206","v207","v208","v209","v210","v211",
          "v212","v213","v214","v215","v216","v217","v218","v219",
          "v220","v221","v222","v223","v224","v225","v226","v227",
          "v228","v229","v230","v231","v232","v233","v234","v235",
          "v236","v237","v238","v239","v240","v241","v242","v243",
          "v244","v245","v246","v247","v248","v249","v250","v251",
          "v252","v253","v254","v255");

    if (tid < 256) {
        h_carry[b * 256 + j] = hout;
        if (t0 + len == T_) hN[b * 256 + j] = hout;
    }
}

// ---------------------------------------------------------------------------
extern "C" void kernel_launch(void* const* d_in, const int* in_sizes, int n_in,
                              void* d_out, int out_size, void* d_ws, size_t ws_size,
                              hipStream_t stream) {
    const float* x   = (const float*)d_in[0];
    const float* h0  = (const float*)d_in[1];
    const float* Wih = (const float*)d_in[2];
    const float* bih = (const float*)d_in[3];
    const float* Whh = (const float*)d_in[4];
    const float* bhh = (const float*)d_in[5];
    float* out = (float*)d_out;
    float* hN  = out + (size_t)B_ * T_ * H_;

    char* ws = (char*)d_ws;
    float*    h_carry = (float*)ws;                       // 65536 B
    uint32_t* Wprep   = (uint32_t*)(ws + 65536);          // 393216 B (48*8 frags * 64 lanes * 16B)
    _Float16* gi      = (_Float16*)(ws + 65536 + 393216);

    const size_t head = 65536 + 393216;
    const size_t per_t = (size_t)B_ * G_ * sizeof(_Float16);  // 98304 B
    size_t avail = (ws_size > head) ? (ws_size - head) : 0;
    if (avail > per_t) avail -= per_t;   // slack: tail prefetch reads one step past chunk
    int tc = (int)(avail / per_t);
    if (tc > T_) tc = T_;
    if (tc < 1)  tc = 1;
    int nch = (T_ + tc - 1) / tc;
    tc = (T_ + nch - 1) / nch;

    hipLaunchKernelGGL(prep_whh_frag, dim3(48, 8), dim3(64), 0, stream, Whh, Wprep);
    for (int t0 = 0; t0 < T_; t0 += tc) {
        int len = (T_ - t0 < tc) ? (T_ - t0) : tc;
        hipLaunchKernelGGL(gemm_gi, dim3(len, 2), dim3(256), 0, stream,
                           x, Wih, bih, bhh, gi, t0);
        const float* hi = (t0 == 0) ? h0 : h_carry;
        hipLaunchKernelGGL(rec_step, dim3(64), dim3(512), 0, stream,
                           Wprep, bhh, gi, hi, out, hN, h_carry, t0, len);
    }
}